// Round 1
// baseline (18512.775 us; speedup 1.0000x reference)
//
#include <hip/hip_runtime.h>

#define BATCH 32
#define NPTS  262144
#define KSAMP 256
#define NF    10
#define INDIM 60
#define HID   768

#define PI_F 3.14159274101257324f  // float(math.pi), 0x40490FDB

// Static device scratch (deterministic: fully rewritten every call before use)
__device__ float g_px[BATCH*NPTS];
__device__ float g_py[BATCH*NPTS];
__device__ float g_pz[BATCH*NPTS];
__device__ float g_dist[BATCH*NPTS];
__device__ float g_samp[BATCH*KSAMP*3];
__device__ float g_enc[(size_t)BATCH*KSAMP*INDIM];
__device__ float g_Wt[INDIM*HID];

// ---------------- prepass: sanitize + AoS->SoA transpose ----------------
__global__ __launch_bounds__(256) void prepass(const float* __restrict__ pc){
  int t = blockIdx.x*256 + threadIdx.x;          // handles points 4t..4t+3
  const float4* src = ((const float4*)pc) + (size_t)t*3;
  float4 a = src[0], b = src[1], c = src[2];
  float v[12] = {a.x,a.y,a.z,a.w,b.x,b.y,b.z,b.w,c.x,c.y,c.z,c.w};
#pragma unroll
  for (int j=0;j<12;j++){
    float m = v[j]*0.0f;          // finite -> 0, inf/nan -> nan (no fast-math fold)
    v[j] = (m == 0.0f) ? v[j] : 0.0f;
  }
  int p = t*4;
  *(float4*)(g_px+p) = make_float4(v[0],v[3],v[6],v[9]);
  *(float4*)(g_py+p) = make_float4(v[1],v[4],v[7],v[10]);
  *(float4*)(g_pz+p) = make_float4(v[2],v[5],v[8],v[11]);
}

// ---------------- FPS ----------------
// Bit-exact vs reference: d = ((x-lx)^2 + (y-ly)^2) + (z-lz)^2, rn each step, no FMA.
__device__ __forceinline__ float dist3(float x,float y,float z,float lx,float ly,float lz){
  float dx=__fsub_rn(x,lx), dy=__fsub_rn(y,ly), dz=__fsub_rn(z,lz);
  return __fadd_rn(__fadd_rn(__fmul_rn(dx,dx),__fmul_rn(dy,dy)),__fmul_rn(dz,dz));
}

template<bool FIRST>
__device__ __forceinline__ void fps_scan(const float* __restrict__ px,
                                         const float* __restrict__ py,
                                         const float* __restrict__ pz,
                                         float* __restrict__ dst,
                                         int tid, float lx, float ly, float lz,
                                         float& bestv_o, int& besti_o){
  float bestv = -1.0f;  // all real distances >= 0
  int   besti = 0;
  for (int i = tid*8; i < NPTS; i += 8192){
    float4 x0 = *(const float4*)(px+i);
    float4 x1 = *(const float4*)(px+i+4);
    float4 y0 = *(const float4*)(py+i);
    float4 y1 = *(const float4*)(py+i+4);
    float4 z0 = *(const float4*)(pz+i);
    float4 z1 = *(const float4*)(pz+i+4);
    float4 o0 = make_float4(0,0,0,0), o1 = make_float4(0,0,0,0);
    if (!FIRST){ o0 = *(const float4*)(dst+i); o1 = *(const float4*)(dst+i+4); }
    float4 n0, n1;
#define FPS_LANE(SX,SY,SZ,OLD,OUT,IDX) { \
      float d_ = dist3(SX,SY,SZ,lx,ly,lz); \
      float nd_; \
      if (FIRST) nd_ = d_; else nd_ = fminf(OLD, d_); \
      OUT = nd_; \
      if (nd_ > bestv){ bestv = nd_; besti = (IDX); } }
    FPS_LANE(x0.x,y0.x,z0.x,o0.x,n0.x,i+0)
    FPS_LANE(x0.y,y0.y,z0.y,o0.y,n0.y,i+1)
    FPS_LANE(x0.z,y0.z,z0.z,o0.z,n0.z,i+2)
    FPS_LANE(x0.w,y0.w,z0.w,o0.w,n0.w,i+3)
    FPS_LANE(x1.x,y1.x,z1.x,o1.x,n1.x,i+4)
    FPS_LANE(x1.y,y1.y,z1.y,o1.y,n1.y,i+5)
    FPS_LANE(x1.z,y1.z,z1.z,o1.z,n1.z,i+6)
    FPS_LANE(x1.w,y1.w,z1.w,o1.w,n1.w,i+7)
#undef FPS_LANE
    *(float4*)(dst+i)   = n0;
    *(float4*)(dst+i+4) = n1;
  }
  bestv_o = bestv; besti_o = besti;
}

__global__ __launch_bounds__(1024) void fps_kernel(){
  const int b   = blockIdx.x;
  const int tid = threadIdx.x;
  const float* __restrict__ px = g_px + (size_t)b*NPTS;
  const float* __restrict__ py = g_py + (size_t)b*NPTS;
  const float* __restrict__ pz = g_pz + (size_t)b*NPTS;
  float* __restrict__ dst = g_dist + (size_t)b*NPTS;

  __shared__ float s_val[16];
  __shared__ int   s_idx[16];
  __shared__ float s_l[3];

  if (tid==0){
    float sx=px[0], sy=py[0], sz=pz[0];
    s_l[0]=sx; s_l[1]=sy; s_l[2]=sz;
    float* sp = &g_samp[((size_t)b*KSAMP)*3];
    sp[0]=sx; sp[1]=sy; sp[2]=sz;
  }
  __syncthreads();
  float lx=s_l[0], ly=s_l[1], lz=s_l[2];

  for (int k=1;k<KSAMP;k++){
    float bestv; int besti;
    if (k==1) fps_scan<true >(px,py,pz,dst,tid,lx,ly,lz,bestv,besti);
    else      fps_scan<false>(px,py,pz,dst,tid,lx,ly,lz,bestv,besti);

    // wave reduce (argmax, first-index tie-break)
#pragma unroll
    for (int off=32; off; off>>=1){
      float ov = __shfl_down(bestv, off);
      int   oi = __shfl_down(besti, off);
      if (ov > bestv || (ov == bestv && oi < besti)){ bestv=ov; besti=oi; }
    }
    if ((tid&63)==0){ s_val[tid>>6]=bestv; s_idx[tid>>6]=besti; }
    __syncthreads();
    if (tid<16){
      bestv = s_val[tid]; besti = s_idx[tid];
#pragma unroll
      for (int off=8; off; off>>=1){
        float ov = __shfl_down(bestv, off, 16);
        int   oi = __shfl_down(besti, off, 16);
        if (ov > bestv || (ov == bestv && oi < besti)){ bestv=ov; besti=oi; }
      }
      if (tid==0){
        float sx=px[besti], sy=py[besti], sz=pz[besti];
        s_l[0]=sx; s_l[1]=sy; s_l[2]=sz;
        float* sp = &g_samp[((size_t)b*KSAMP + k)*3];
        sp[0]=sx; sp[1]=sy; sp[2]=sz;
      }
    }
    __syncthreads();
    lx=s_l[0]; ly=s_l[1]; lz=s_l[2];
  }
}

// ---------------- normalize + Fourier encode ----------------
template<int OP>  // 0 sum, 1 max, 2 min
__device__ __forceinline__ float blk_red(float v, float* s4){
  int tid = threadIdx.x;
#pragma unroll
  for (int off=32; off; off>>=1){
    float o = __shfl_down(v, off);
    v = (OP==0) ? v+o : ((OP==1) ? fmaxf(v,o) : fminf(v,o));
  }
  if ((tid&63)==0) s4[tid>>6] = v;
  __syncthreads();
  float r0=s4[0], r1=s4[1], r2=s4[2], r3=s4[3];
  float r = (OP==0) ? ((r0+r1)+(r2+r3))
          : ((OP==1) ? fmaxf(fmaxf(r0,r1),fmaxf(r2,r3))
                     : fminf(fminf(r0,r1),fminf(r2,r3)));
  __syncthreads();
  return r;
}

__global__ __launch_bounds__(256) void norm_encode(){
  __shared__ float s4[4];
  int b = blockIdx.x, k = threadIdx.x;
  const float* sp = &g_samp[((size_t)b*KSAMP + k)*3];
  float x = sp[0], y = sp[1], z = sp[2];

  float cx = blk_red<0>(x, s4) * (1.0f/KSAMP);
  float cy = blk_red<0>(y, s4) * (1.0f/KSAMP);
  float cz = blk_red<0>(z, s4) * (1.0f/KSAMP);

  float ux = __fsub_rn(x,cx), uy = __fsub_rn(y,cy), uz = __fsub_rn(z,cz);

  float mxx = blk_red<1>(ux, s4), mnx = blk_red<2>(ux, s4);
  float mxy = blk_red<1>(uy, s4), mny = blk_red<2>(uy, s4);
  float mxz = blk_red<1>(uz, s4), mnz = blk_red<2>(uz, s4);
  float bx = __fsub_rn(mxx,mnx), by = __fsub_rn(mxy,mny), bz = __fsub_rn(mxz,mnz);
  float md = fmaxf(fmaxf(bx,by),bz);
  float scale = (md > 1e-8f) ? md : 1.0f;

  float n3[3] = { __fdiv_rn(ux,scale), __fdiv_rn(uy,scale), __fdiv_rn(uz,scale) };

  float* e = &g_enc[((size_t)b*KSAMP + k)*INDIM];
#pragma unroll
  for (int c=0;c<3;c++){
    float base = n3[c];
#pragma unroll
    for (int f=0; f<NF; f++){
      float t = __fmul_rn(base, (float)(1<<f));
      float a = __fmul_rn(t, PI_F);
      e[c*2*NF + f*2 + 0] = sinf(a);
      e[c*2*NF + f*2 + 1] = cosf(a);
    }
  }
}

// ---------------- W transpose + GEMM ----------------
__global__ __launch_bounds__(256) void wtrans(const float* __restrict__ W){
  int idx = blockIdx.x*256 + threadIdx.x;   // < 60*768 = 46080
  int d = idx / HID;
  int h = idx - d*HID;
  g_Wt[idx] = W[h*INDIM + d];
}

__global__ __launch_bounds__(256) void gemm_kernel(const float* __restrict__ bias,
                                                   float* __restrict__ out){
  __shared__ float s_enc[4*INDIM];
  int blk = blockIdx.x, tid = threadIdx.x;
  int row0 = blk*4;                         // 4 (b,k) rows per block
  if (tid < 4*INDIM) s_enc[tid] = g_enc[(size_t)row0*INDIM + tid];
  __syncthreads();

  float acc[4][3] = {};
  for (int d=0; d<INDIM; d++){
    float w0 = g_Wt[d*HID + tid];
    float w1 = g_Wt[d*HID + tid + 256];
    float w2 = g_Wt[d*HID + tid + 512];
#pragma unroll
    for (int r=0;r<4;r++){
      float ev = s_enc[r*INDIM + d];
      acc[r][0] = fmaf(ev, w0, acc[r][0]);
      acc[r][1] = fmaf(ev, w1, acc[r][1]);
      acc[r][2] = fmaf(ev, w2, acc[r][2]);
    }
  }
  float b0=bias[tid], b1=bias[tid+256], b2=bias[tid+512];
#pragma unroll
  for (int r=0;r<4;r++){
    size_t o = (size_t)(row0+r)*HID;
    out[o+tid]     = acc[r][0]+b0;
    out[o+tid+256] = acc[r][1]+b1;
    out[o+tid+512] = acc[r][2]+b2;
  }
}

// ---------------- launch ----------------
extern "C" void kernel_launch(void* const* d_in, const int* in_sizes, int n_in,
                              void* d_out, int out_size, void* d_ws, size_t ws_size,
                              hipStream_t stream){
  const float* pc   = (const float*)d_in[0];
  const float* W    = (const float*)d_in[1];
  const float* bias = (const float*)d_in[2];
  float* out = (float*)d_out;

  prepass<<<(BATCH*NPTS/4)/256, 256, 0, stream>>>(pc);
  wtrans <<<(INDIM*HID)/256,    256, 0, stream>>>(W);
  fps_kernel <<<BATCH, 1024, 0, stream>>>();
  norm_encode<<<BATCH, KSAMP, 0, stream>>>();
  gemm_kernel<<<(BATCH*KSAMP)/4, 256, 0, stream>>>(bias, out);
}

// Round 2
// 8385.442 us; speedup vs baseline: 2.2077x; 2.2077x over previous
//
#include <hip/hip_runtime.h>

#define BATCH 32
#define NPTS  262144
#define KSAMP 256
#define NF    10
#define INDIM 60
#define HID   768

#define NBLK_PER_B 8
#define SLICE (NPTS/NBLK_PER_B)   // 32768 points per block
#define PPT   32                  // points per thread (register-resident dists)

#define PI_F 3.14159274101257324f  // float(math.pi)

// Static device scratch (fully rewritten every call before use)
__device__ float g_px[BATCH*NPTS];
__device__ float g_py[BATCH*NPTS];
__device__ float g_pz[BATCH*NPTS];
__device__ float g_samp[BATCH*KSAMP*3];
__device__ float g_enc[(size_t)BATCH*KSAMP*INDIM];
__device__ float g_Wt[INDIM*HID];
__device__ unsigned long long g_cand[BATCH][2][NBLK_PER_B]; // [parity][slice]
__device__ int g_arrive[BATCH];                              // monotonic barrier counters

// ---------------- prepass: sanitize + AoS->SoA transpose ----------------
__global__ __launch_bounds__(256) void prepass(const float* __restrict__ pc){
  int t = blockIdx.x*256 + threadIdx.x;          // handles points 4t..4t+3
  const float4* src = ((const float4*)pc) + (size_t)t*3;
  float4 a = src[0], b = src[1], c = src[2];
  float v[12] = {a.x,a.y,a.z,a.w,b.x,b.y,b.z,b.w,c.x,c.y,c.z,c.w};
#pragma unroll
  for (int j=0;j<12;j++){
    float m = v[j]*0.0f;          // finite -> 0, inf/nan -> nan
    v[j] = (m == 0.0f) ? v[j] : 0.0f;
  }
  int p = t*4;
  *(float4*)(g_px+p) = make_float4(v[0],v[3],v[6],v[9]);
  *(float4*)(g_py+p) = make_float4(v[1],v[4],v[7],v[10]);
  *(float4*)(g_pz+p) = make_float4(v[2],v[5],v[8],v[11]);
}

__global__ void init_barriers(){
  if (threadIdx.x < BATCH) g_arrive[threadIdx.x] = 0;
}

// ---------------- FPS ----------------
// Bit-exact vs reference: d = ((x-lx)^2 + (y-ly)^2) + (z-lz)^2, rn each step, no FMA.
__device__ __forceinline__ float dist3(float x,float y,float z,float lx,float ly,float lz){
  float dx=__fsub_rn(x,lx), dy=__fsub_rn(y,ly), dz=__fsub_rn(z,lz);
  return __fadd_rn(__fadd_rn(__fmul_rn(dx,dx),__fmul_rn(dy,dy)),__fmul_rn(dz,dz));
}

__global__ __launch_bounds__(1024, 4) void fps_kernel(int /*unused*/){
  const int blk = blockIdx.x;
  const int b   = blk >> 3;          // batch
  const int s   = blk & 7;           // slice
  const int tid = threadIdx.x;
  const float* __restrict__ px = g_px + (size_t)b*NPTS;
  const float* __restrict__ py = g_py + (size_t)b*NPTS;
  const float* __restrict__ pz = g_pz + (size_t)b*NPTS;
  const int soff = s*SLICE;

  __shared__ float s_val[16];
  __shared__ int   s_idx[16];
  __shared__ float s_last[3];

  // register-resident running min-distances (matches dists0 = inf)
  float d[PPT];
#pragma unroll
  for (int i=0;i<PPT;i++) d[i] = __builtin_huge_valf();

  // first sample = point 0 (same address for all threads -> broadcast load)
  float lx = px[0], ly = py[0], lz = pz[0];
  if (s==0 && tid==0){
    float* sp = &g_samp[(size_t)b*KSAMP*3];
    sp[0]=lx; sp[1]=ly; sp[2]=lz;
  }

  for (int k=1; k<KSAMP; k++){
    float bestv = -1.0f; int besti = 0;
#pragma unroll
    for (int j=0;j<8;j++){
      int base = soff + j*4096 + tid*4;
      float4 X = *(const float4*)(px+base);
      float4 Y = *(const float4*)(py+base);
      float4 Z = *(const float4*)(pz+base);
      float xs[4]={X.x,X.y,X.z,X.w};
      float ys[4]={Y.x,Y.y,Y.z,Y.w};
      float zs[4]={Z.x,Z.y,Z.z,Z.w};
#pragma unroll
      for (int c=0;c<4;c++){
        float dd = dist3(xs[c],ys[c],zs[c],lx,ly,lz);
        float nd = fminf(d[j*4+c], dd);
        d[j*4+c] = nd;
        if (nd > bestv){ bestv = nd; besti = base + c; }  // strict > => first index on tie
      }
    }
    // intra-wave argmax reduce (first-index tie-break)
#pragma unroll
    for (int off=32; off; off>>=1){
      float ov = __shfl_down(bestv, off);
      int   oi = __shfl_down(besti, off);
      if (ov > bestv || (ov == bestv && oi < besti)){ bestv=ov; besti=oi; }
    }
    if ((tid&63)==0){ s_val[tid>>6]=bestv; s_idx[tid>>6]=besti; }
    __syncthreads();
    if (tid==0){
      // cross-wave reduce (thread0 holds wave 0 result already)
      for (int w=1; w<16; w++){
        float ov=s_val[w]; int oi=s_idx[w];
        if (ov > bestv || (ov == bestv && oi < besti)){ bestv=ov; besti=oi; }
      }
      // publish packed key: larger key = (bigger val, then smaller idx)
      unsigned long long key = ((unsigned long long)__float_as_uint(bestv) << 32)
                             | (unsigned long long)(0xFFFFFFFFu - (unsigned)besti);
      __hip_atomic_store(&g_cand[b][k&1][s], key, __ATOMIC_RELAXED, __HIP_MEMORY_SCOPE_AGENT);
      __threadfence();
      __hip_atomic_fetch_add(&g_arrive[b], 1, __ATOMIC_RELEASE, __HIP_MEMORY_SCOPE_AGENT);
      const int target = 8*k;
      while (__hip_atomic_load(&g_arrive[b], __ATOMIC_ACQUIRE, __HIP_MEMORY_SCOPE_AGENT) < target)
        __builtin_amdgcn_s_sleep(1);
      unsigned long long bk = 0;
      for (int q=0;q<NBLK_PER_B;q++){
        unsigned long long kq = __hip_atomic_load(&g_cand[b][k&1][q],
                                 __ATOMIC_RELAXED, __HIP_MEMORY_SCOPE_AGENT);
        if (kq > bk) bk = kq;
      }
      int w = (int)(0xFFFFFFFFu - (unsigned)(bk & 0xFFFFFFFFull));
      float wx = px[w], wy = py[w], wz = pz[w];
      s_last[0]=wx; s_last[1]=wy; s_last[2]=wz;
      if (s==0){
        float* sp = &g_samp[((size_t)b*KSAMP + k)*3];
        sp[0]=wx; sp[1]=wy; sp[2]=wz;
      }
    }
    __syncthreads();
    lx=s_last[0]; ly=s_last[1]; lz=s_last[2];
  }
}

// ---------------- normalize + Fourier encode ----------------
template<int OP>  // 0 sum, 1 max, 2 min
__device__ __forceinline__ float blk_red(float v, float* s4){
  int tid = threadIdx.x;
#pragma unroll
  for (int off=32; off; off>>=1){
    float o = __shfl_down(v, off);
    v = (OP==0) ? v+o : ((OP==1) ? fmaxf(v,o) : fminf(v,o));
  }
  if ((tid&63)==0) s4[tid>>6] = v;
  __syncthreads();
  float r0=s4[0], r1=s4[1], r2=s4[2], r3=s4[3];
  float r = (OP==0) ? ((r0+r1)+(r2+r3))
          : ((OP==1) ? fmaxf(fmaxf(r0,r1),fmaxf(r2,r3))
                     : fminf(fminf(r0,r1),fminf(r2,r3)));
  __syncthreads();
  return r;
}

__global__ __launch_bounds__(256) void norm_encode(){
  __shared__ float s4[4];
  int b = blockIdx.x, k = threadIdx.x;
  const float* sp = &g_samp[((size_t)b*KSAMP + k)*3];
  float x = sp[0], y = sp[1], z = sp[2];

  float cx = blk_red<0>(x, s4) * (1.0f/KSAMP);
  float cy = blk_red<0>(y, s4) * (1.0f/KSAMP);
  float cz = blk_red<0>(z, s4) * (1.0f/KSAMP);

  float ux = __fsub_rn(x,cx), uy = __fsub_rn(y,cy), uz = __fsub_rn(z,cz);

  float mxx = blk_red<1>(ux, s4), mnx = blk_red<2>(ux, s4);
  float mxy = blk_red<1>(uy, s4), mny = blk_red<2>(uy, s4);
  float mxz = blk_red<1>(uz, s4), mnz = blk_red<2>(uz, s4);
  float bx = __fsub_rn(mxx,mnx), by = __fsub_rn(mxy,mny), bz = __fsub_rn(mxz,mnz);
  float md = fmaxf(fmaxf(bx,by),bz);
  float scale = (md > 1e-8f) ? md : 1.0f;

  float n3[3] = { __fdiv_rn(ux,scale), __fdiv_rn(uy,scale), __fdiv_rn(uz,scale) };

  float* e = &g_enc[((size_t)b*KSAMP + k)*INDIM];
#pragma unroll
  for (int c=0;c<3;c++){
    float base = n3[c];
#pragma unroll
    for (int f=0; f<NF; f++){
      float t = __fmul_rn(base, (float)(1<<f));
      float a = __fmul_rn(t, PI_F);
      e[c*2*NF + f*2 + 0] = sinf(a);
      e[c*2*NF + f*2 + 1] = cosf(a);
    }
  }
}

// ---------------- W transpose + GEMM ----------------
__global__ __launch_bounds__(256) void wtrans(const float* __restrict__ W){
  int idx = blockIdx.x*256 + threadIdx.x;   // < 60*768 = 46080
  int d = idx / HID;
  int h = idx - d*HID;
  g_Wt[idx] = W[h*INDIM + d];
}

__global__ __launch_bounds__(256) void gemm_kernel(const float* __restrict__ bias,
                                                   float* __restrict__ out){
  __shared__ float s_enc[4*INDIM];
  int blk = blockIdx.x, tid = threadIdx.x;
  int row0 = blk*4;                         // 4 (b,k) rows per block
  if (tid < 4*INDIM) s_enc[tid] = g_enc[(size_t)row0*INDIM + tid];
  __syncthreads();

  float acc[4][3] = {};
  for (int d=0; d<INDIM; d++){
    float w0 = g_Wt[d*HID + tid];
    float w1 = g_Wt[d*HID + tid + 256];
    float w2 = g_Wt[d*HID + tid + 512];
#pragma unroll
    for (int r=0;r<4;r++){
      float ev = s_enc[r*INDIM + d];
      acc[r][0] = fmaf(ev, w0, acc[r][0]);
      acc[r][1] = fmaf(ev, w1, acc[r][1]);
      acc[r][2] = fmaf(ev, w2, acc[r][2]);
    }
  }
  float b0=bias[tid], b1=bias[tid+256], b2=bias[tid+512];
#pragma unroll
  for (int r=0;r<4;r++){
    size_t o = (size_t)(row0+r)*HID;
    out[o+tid]     = acc[r][0]+b0;
    out[o+tid+256] = acc[r][1]+b1;
    out[o+tid+512] = acc[r][2]+b2;
  }
}

// ---------------- launch ----------------
extern "C" void kernel_launch(void* const* d_in, const int* in_sizes, int n_in,
                              void* d_out, int out_size, void* d_ws, size_t ws_size,
                              hipStream_t stream){
  const float* pc   = (const float*)d_in[0];
  const float* W    = (const float*)d_in[1];
  const float* bias = (const float*)d_in[2];
  float* out = (float*)d_out;

  prepass<<<(BATCH*NPTS/4)/256, 256, 0, stream>>>(pc);
  wtrans <<<(INDIM*HID)/256,    256, 0, stream>>>(W);
  init_barriers<<<1, 64, 0, stream>>>();

  int dummy = 0;
  void* args[] = { &dummy };
  hipLaunchCooperativeKernel((void*)fps_kernel, dim3(BATCH*NBLK_PER_B), dim3(1024),
                             args, 0, stream);

  norm_encode<<<BATCH, KSAMP, 0, stream>>>();
  gemm_kernel<<<(BATCH*KSAMP)/4, 256, 0, stream>>>(bias, out);
}

// Round 3
// 4336.258 us; speedup vs baseline: 4.2693x; 1.9338x over previous
//
#include <hip/hip_runtime.h>

#define BATCH 32
#define NPTS  262144
#define KSAMP 256
#define NF    10
#define INDIM 60
#define HID   768

#define NBLK_PER_B 8
#define SLICE (NPTS/NBLK_PER_B)   // 32768 points per block (one CU)
// per-thread point layout: groups of 4 pts; j=0..4 regs (20), j=5 LDS (4), j=6..7 global (8)
#define REG_G 5
#define LDS_G 1
#define GLB_G 2

#define PI_F 3.14159274101257324f  // float(math.pi)

// Static device scratch (rewritten every call before use)
__device__ float g_px[BATCH*NPTS];   // only region [soff+24576, soff+32768) used
__device__ float g_py[BATCH*NPTS];
__device__ float g_pz[BATCH*NPTS];
__device__ float g_samp[BATCH*KSAMP*3];
__device__ float g_enc[(size_t)BATCH*KSAMP*INDIM];
__device__ float g_Wt[INDIM*HID];
__device__ unsigned long long g_slot[BATCH][2][NBLK_PER_B]; // [parity][slice], tag k in [63:56]

__device__ __forceinline__ float san(float v){
  float m = v*0.0f;                 // finite -> 0, inf/nan -> nan (no fast-math fold)
  return (m == 0.0f) ? v : 0.0f;
}

// ---------------- region prepass: sanitize + SoA for global-resident 1/4 ----------------
__global__ __launch_bounds__(256) void region_prepass(const float* __restrict__ pc){
  int bid = blockIdx.x;             // 2048 blocks
  int b   = bid >> 6;               // 64 blocks per batch
  int rem = bid & 63;
  int q   = rem*1024 + threadIdx.x*4;   // 0..65535 region-local
  int s   = q >> 13;
  int o   = q & 8191;
  int p   = s*SLICE + (REG_G+LDS_G)*4096 + o;  // global point index in batch
  const float* src = pc + ((size_t)b*NPTS + p)*3;
  float4 A = *(const float4*)(src);
  float4 Bv= *(const float4*)(src+4);
  float4 C = *(const float4*)(src+8);
  float v[12] = {A.x,A.y,A.z,A.w,Bv.x,Bv.y,Bv.z,Bv.w,C.x,C.y,C.z,C.w};
#pragma unroll
  for (int j=0;j<12;j++) v[j] = san(v[j]);
  size_t base = (size_t)b*NPTS + p;
  *(float4*)(g_px+base) = make_float4(v[0],v[3],v[6],v[9]);
  *(float4*)(g_py+base) = make_float4(v[1],v[4],v[7],v[10]);
  *(float4*)(g_pz+base) = make_float4(v[2],v[5],v[8],v[11]);
}

// ---------------- W transpose + slot clear ----------------
__global__ __launch_bounds__(256) void wtrans(const float* __restrict__ W){
  int idx = blockIdx.x*256 + threadIdx.x;   // < 60*768 = 46080
  int d = idx / HID;
  int h = idx - d*HID;
  g_Wt[idx] = W[h*INDIM + d];
  if (blockIdx.x == 0 && threadIdx.x < 256){
    ((unsigned long long*)g_slot)[threadIdx.x*2+0] = 0ull;
    ((unsigned long long*)g_slot)[threadIdx.x*2+1] = 0ull;
  }
}

// ---------------- FPS ----------------
// Bit-exact vs reference: d = ((x-lx)^2 + (y-ly)^2) + (z-lz)^2, rn each step, no FMA.
__device__ __forceinline__ float dist3(float x,float y,float z,float lx,float ly,float lz){
  float dx=__fsub_rn(x,lx), dy=__fsub_rn(y,ly), dz=__fsub_rn(z,lz);
  return __fadd_rn(__fadd_rn(__fmul_rn(dx,dx),__fmul_rn(dy,dy)),__fmul_rn(dz,dz));
}

__global__ __launch_bounds__(1024) void fps_kernel(const float* __restrict__ pc){
  __shared__ float4 sx[1024], sy[1024], sz[1024];   // 48 KB coord planes
  __shared__ float s_val[16];
  __shared__ int   s_idx[16];
  __shared__ float s_last[3];

  const int blk = blockIdx.x;
  const int b   = blk >> 3;          // batch
  const int s   = blk & 7;           // slice
  const int tid = threadIdx.x;
  const int lane = tid & 63, wave = tid >> 6;
  const size_t bN = (size_t)b*NPTS;
  const int soff = s*SLICE;

  // ---- one-time load: regs (j=0..4) and LDS (j=5), sanitized, from AoS pc ----
  float rx[REG_G*4], ry[REG_G*4], rz[REG_G*4];
#pragma unroll
  for (int j=0;j<REG_G+LDS_G;j++){
    int p0 = soff + j*4096 + tid*4;
    const float* src = pc + (bN + p0)*3;
    float4 A = *(const float4*)(src);
    float4 Bv= *(const float4*)(src+4);
    float4 C = *(const float4*)(src+8);
    float v[12] = {A.x,A.y,A.z,A.w,Bv.x,Bv.y,Bv.z,Bv.w,C.x,C.y,C.z,C.w};
#pragma unroll
    for (int q=0;q<12;q++) v[q] = san(v[q]);
    if (j < REG_G){
#pragma unroll
      for (int c=0;c<4;c++){ rx[j*4+c]=v[3*c]; ry[j*4+c]=v[3*c+1]; rz[j*4+c]=v[3*c+2]; }
    } else {
      sx[tid] = make_float4(v[0],v[3],v[6],v[9]);
      sy[tid] = make_float4(v[1],v[4],v[7],v[10]);
      sz[tid] = make_float4(v[2],v[5],v[8],v[11]);
    }
  }

  float d[32];
#pragma unroll
  for (int i=0;i<32;i++) d[i] = __builtin_huge_valf();

  // first sample = sanitized point 0 (uniform scalar loads)
  float lx = san(pc[bN*3+0]), ly = san(pc[bN*3+1]), lz = san(pc[bN*3+2]);
  if (s==0 && tid<3) g_samp[(size_t)b*KSAMP*3 + tid] = san(pc[bN*3 + tid]);
  __syncthreads();   // LDS coords visible

  for (int k=1; k<KSAMP; k++){
    // issue far loads first (L2-resident region)
    size_t gb = bN + soff + (size_t)(REG_G+LDS_G)*4096 + tid*4;
    float4 gx0 = *(const float4*)(g_px+gb),       gx1 = *(const float4*)(g_px+gb+4096);
    float4 gy0 = *(const float4*)(g_py+gb),       gy1 = *(const float4*)(g_py+gb+4096);
    float4 gz0 = *(const float4*)(g_pz+gb),       gz1 = *(const float4*)(g_pz+gb+4096);
    float4 X = sx[tid], Y = sy[tid], Z = sz[tid];

    float bestv = -1.0f; int besti = 0;
#define UPD(DX,DY,DZ,DI,IDX) { \
      float dd_ = dist3(DX,DY,DZ,lx,ly,lz); \
      float nd_ = fminf(d[DI], dd_); \
      d[DI] = nd_; \
      if (nd_ > bestv){ bestv = nd_; besti = (IDX); } }
    // register groups
#pragma unroll
    for (int j=0;j<REG_G;j++){
#pragma unroll
      for (int c=0;c<4;c++)
        UPD(rx[j*4+c], ry[j*4+c], rz[j*4+c], j*4+c, soff + j*4096 + tid*4 + c)
    }
    // LDS group (j = REG_G)
    {
      float xs[4]={X.x,X.y,X.z,X.w}, ys[4]={Y.x,Y.y,Y.z,Y.w}, zs[4]={Z.x,Z.y,Z.z,Z.w};
#pragma unroll
      for (int c=0;c<4;c++)
        UPD(xs[c], ys[c], zs[c], REG_G*4+c, soff + REG_G*4096 + tid*4 + c)
    }
    // global groups
    {
      float xs[4]={gx0.x,gx0.y,gx0.z,gx0.w}, ys[4]={gy0.x,gy0.y,gy0.z,gy0.w}, zs[4]={gz0.x,gz0.y,gz0.z,gz0.w};
#pragma unroll
      for (int c=0;c<4;c++)
        UPD(xs[c], ys[c], zs[c], (REG_G+1)*4+c, soff + (REG_G+1)*4096 + tid*4 + c)
    }
    {
      float xs[4]={gx1.x,gx1.y,gx1.z,gx1.w}, ys[4]={gy1.x,gy1.y,gy1.z,gy1.w}, zs[4]={gz1.x,gz1.y,gz1.z,gz1.w};
#pragma unroll
      for (int c=0;c<4;c++)
        UPD(xs[c], ys[c], zs[c], (REG_G+2)*4+c, soff + (REG_G+2)*4096 + tid*4 + c)
    }
#undef UPD

    // intra-wave argmax (first-index tie-break)
#pragma unroll
    for (int off=32; off; off>>=1){
      float ov = __shfl_down(bestv, off);
      int   oi = __shfl_down(besti, off);
      if (ov > bestv || (ov == bestv && oi < besti)){ bestv=ov; besti=oi; }
    }
    if (lane==0){ s_val[wave]=bestv; s_idx[wave]=besti; }
    __syncthreads();

    if (wave==0){
      // 16-lane cross-wave reduce (butterfly -> all lanes hold block candidate)
      float bv = s_val[lane & 15]; int bi = s_idx[lane & 15];
#pragma unroll
      for (int m=8; m; m>>=1){
        float ov = __shfl_xor(bv, m);
        int   oi = __shfl_xor(bi, m);
        if (ov > bv || (ov == bv && oi < bi)){ bv=ov; bi=oi; }
      }
      // publish packed candidate: [k:8][val:32][0xFFFFFF^idx:24]
      unsigned long long key = ((unsigned long long)(unsigned)k << 56)
                             | ((unsigned long long)__float_as_uint(bv) << 24)
                             | (unsigned long long)(0xFFFFFFu ^ (unsigned)bi);
      if (lane==0)
        __hip_atomic_store(&g_slot[b][k&1][s], key, __ATOMIC_RELEASE, __HIP_MEMORY_SCOPE_AGENT);
      // parallel poll: lane q watches slice q
      unsigned long long pay = 0;
      if (lane < NBLK_PER_B){
        unsigned long long v;
        do {
          v = __hip_atomic_load(&g_slot[b][k&1][lane], __ATOMIC_RELAXED, __HIP_MEMORY_SCOPE_AGENT);
        } while ((unsigned)(v >> 56) != (unsigned)k);
        pay = v & 0x00FFFFFFFFFFFFFFull;
      }
      // 8-lane max butterfly on payload (u64 via 2x32 shuffles)
#pragma unroll
      for (int m=4; m; m>>=1){
        unsigned lo = (unsigned)pay, hi = (unsigned)(pay >> 32);
        unsigned lo2 = __shfl_xor(lo, m), hi2 = __shfl_xor(hi, m);
        unsigned long long o = ((unsigned long long)hi2 << 32) | lo2;
        if (o > pay) pay = o;
      }
      int w = (int)(0xFFFFFFu ^ (unsigned)(pay & 0xFFFFFFu));
      if (lane < 3){
        float cv = san(pc[(bN + (size_t)w)*3 + lane]);
        s_last[lane] = cv;
        if (s==0) g_samp[((size_t)b*KSAMP + k)*3 + lane] = cv;
      }
    }
    __syncthreads();
    lx=s_last[0]; ly=s_last[1]; lz=s_last[2];
  }
}

// ---------------- normalize + Fourier encode ----------------
template<int OP>  // 0 sum, 1 max, 2 min
__device__ __forceinline__ float blk_red(float v, float* s4){
  int tid = threadIdx.x;
#pragma unroll
  for (int off=32; off; off>>=1){
    float o = __shfl_down(v, off);
    v = (OP==0) ? v+o : ((OP==1) ? fmaxf(v,o) : fminf(v,o));
  }
  if ((tid&63)==0) s4[tid>>6] = v;
  __syncthreads();
  float r0=s4[0], r1=s4[1], r2=s4[2], r3=s4[3];
  float r = (OP==0) ? ((r0+r1)+(r2+r3))
          : ((OP==1) ? fmaxf(fmaxf(r0,r1),fmaxf(r2,r3))
                     : fminf(fminf(r0,r1),fminf(r2,r3)));
  __syncthreads();
  return r;
}

__global__ __launch_bounds__(256) void norm_encode(){
  __shared__ float s4[4];
  int b = blockIdx.x, k = threadIdx.x;
  const float* sp = &g_samp[((size_t)b*KSAMP + k)*3];
  float x = sp[0], y = sp[1], z = sp[2];

  float cx = blk_red<0>(x, s4) * (1.0f/KSAMP);
  float cy = blk_red<0>(y, s4) * (1.0f/KSAMP);
  float cz = blk_red<0>(z, s4) * (1.0f/KSAMP);

  float ux = __fsub_rn(x,cx), uy = __fsub_rn(y,cy), uz = __fsub_rn(z,cz);

  float mxx = blk_red<1>(ux, s4), mnx = blk_red<2>(ux, s4);
  float mxy = blk_red<1>(uy, s4), mny = blk_red<2>(uy, s4);
  float mxz = blk_red<1>(uz, s4), mnz = blk_red<2>(uz, s4);
  float bx = __fsub_rn(mxx,mnx), by = __fsub_rn(mxy,mny), bz = __fsub_rn(mxz,mnz);
  float md = fmaxf(fmaxf(bx,by),bz);
  float scale = (md > 1e-8f) ? md : 1.0f;

  float n3[3] = { __fdiv_rn(ux,scale), __fdiv_rn(uy,scale), __fdiv_rn(uz,scale) };

  float* e = &g_enc[((size_t)b*KSAMP + k)*INDIM];
#pragma unroll
  for (int c=0;c<3;c++){
    float base = n3[c];
#pragma unroll
    for (int f=0; f<NF; f++){
      float t = __fmul_rn(base, (float)(1<<f));
      float a = __fmul_rn(t, PI_F);
      e[c*2*NF + f*2 + 0] = sinf(a);
      e[c*2*NF + f*2 + 1] = cosf(a);
    }
  }
}

// ---------------- GEMM ----------------
__global__ __launch_bounds__(256) void gemm_kernel(const float* __restrict__ bias,
                                                   float* __restrict__ out){
  __shared__ float s_enc[4*INDIM];
  int blk = blockIdx.x, tid = threadIdx.x;
  int row0 = blk*4;                         // 4 (b,k) rows per block
  if (tid < 4*INDIM) s_enc[tid] = g_enc[(size_t)row0*INDIM + tid];
  __syncthreads();

  float acc[4][3] = {};
  for (int d=0; d<INDIM; d++){
    float w0 = g_Wt[d*HID + tid];
    float w1 = g_Wt[d*HID + tid + 256];
    float w2 = g_Wt[d*HID + tid + 512];
#pragma unroll
    for (int r=0;r<4;r++){
      float ev = s_enc[r*INDIM + d];
      acc[r][0] = fmaf(ev, w0, acc[r][0]);
      acc[r][1] = fmaf(ev, w1, acc[r][1]);
      acc[r][2] = fmaf(ev, w2, acc[r][2]);
    }
  }
  float b0=bias[tid], b1=bias[tid+256], b2=bias[tid+512];
#pragma unroll
  for (int r=0;r<4;r++){
    size_t o = (size_t)(row0+r)*HID;
    out[o+tid]     = acc[r][0]+b0;
    out[o+tid+256] = acc[r][1]+b1;
    out[o+tid+512] = acc[r][2]+b2;
  }
}

// ---------------- launch ----------------
extern "C" void kernel_launch(void* const* d_in, const int* in_sizes, int n_in,
                              void* d_out, int out_size, void* d_ws, size_t ws_size,
                              hipStream_t stream){
  const float* pc   = (const float*)d_in[0];
  const float* W    = (const float*)d_in[1];
  const float* bias = (const float*)d_in[2];
  float* out = (float*)d_out;

  region_prepass<<<2048, 256, 0, stream>>>(pc);
  wtrans        <<<(INDIM*HID)/256, 256, 0, stream>>>(W);

  void* args[] = { (void*)&pc };
  hipLaunchCooperativeKernel((void*)fps_kernel, dim3(BATCH*NBLK_PER_B), dim3(1024),
                             args, 0, stream);

  norm_encode<<<BATCH, KSAMP, 0, stream>>>();
  gemm_kernel<<<(BATCH*KSAMP)/4, 256, 0, stream>>>(bias, out);
}

// Round 4
// 2485.614 us; speedup vs baseline: 7.4480x; 1.7445x over previous
//
#include <hip/hip_runtime.h>

#define BATCH 32
#define NPTS  262144
#define KSAMP 256
#define NF    10
#define INDIM 60
#define HID   768

#define NBLK_PER_B 8
#define SLICE (NPTS/NBLK_PER_B)   // 32768 points per block (one CU)
// per-thread point layout: 8 groups of 4 pts
//   j=0..3  -> registers (16 pts, 48 VGPRs)
//   j=4..6  -> LDS       (12 pts, 144 KB)
//   j=7     -> global SoA (4 pts, 48 KB/CU, L2-resident)
#define REG_G 4
#define LDS_G 3

#define PI_F 3.14159274101257324f  // float(math.pi)

// Static device scratch (rewritten every call before use)
__device__ float g_px[BATCH*NPTS];   // only group j=7 regions used
__device__ float g_py[BATCH*NPTS];
__device__ float g_pz[BATCH*NPTS];
__device__ float g_samp[BATCH*KSAMP*3];
__device__ float g_enc[(size_t)BATCH*KSAMP*INDIM];
__device__ float g_Wt[INDIM*HID];
__device__ unsigned long long g_slot[BATCH][2][NBLK_PER_B]; // [parity][slice], tag k in [63:56]

__device__ __forceinline__ float san(float v){
  float m = v*0.0f;                 // finite -> 0, inf/nan -> nan (no fast-math fold)
  return (m == 0.0f) ? v : 0.0f;
}

// ---------------- region prepass: sanitize + SoA for global-resident 1/8 ----------------
__global__ __launch_bounds__(256) void region_prepass(const float* __restrict__ pc){
  int bid = blockIdx.x;             // 1024 blocks
  int b   = bid >> 5;               // 32 blocks per batch
  int rem = bid & 31;
  int q   = rem*1024 + threadIdx.x*4;   // 0..32767 region-local (per batch)
  int s   = q >> 12;                    // slice (4096 pts of group 7 per slice)
  int o   = q & 4095;
  int p   = s*SLICE + 7*4096 + o;       // global point index in batch
  const float* src = pc + ((size_t)b*NPTS + p)*3;
  float4 A = *(const float4*)(src);
  float4 Bv= *(const float4*)(src+4);
  float4 C = *(const float4*)(src+8);
  float v[12] = {A.x,A.y,A.z,A.w,Bv.x,Bv.y,Bv.z,Bv.w,C.x,C.y,C.z,C.w};
#pragma unroll
  for (int j=0;j<12;j++) v[j] = san(v[j]);
  size_t base = (size_t)b*NPTS + p;
  *(float4*)(g_px+base) = make_float4(v[0],v[3],v[6],v[9]);
  *(float4*)(g_py+base) = make_float4(v[1],v[4],v[7],v[10]);
  *(float4*)(g_pz+base) = make_float4(v[2],v[5],v[8],v[11]);
}

// ---------------- W transpose + slot clear ----------------
__global__ __launch_bounds__(256) void wtrans(const float* __restrict__ W){
  int idx = blockIdx.x*256 + threadIdx.x;   // < 60*768 = 46080
  int d = idx / HID;
  int h = idx - d*HID;
  g_Wt[idx] = W[h*INDIM + d];
  if (blockIdx.x == 0 && threadIdx.x < 256){
    ((unsigned long long*)g_slot)[threadIdx.x*2+0] = 0ull;
    ((unsigned long long*)g_slot)[threadIdx.x*2+1] = 0ull;
  }
}

// ---------------- FPS ----------------
// Bit-exact vs reference: d = ((x-lx)^2 + (y-ly)^2) + (z-lz)^2, rn each step, no FMA.
__device__ __forceinline__ float dist3(float x,float y,float z,float lx,float ly,float lz){
  float dx=__fsub_rn(x,lx), dy=__fsub_rn(y,ly), dz=__fsub_rn(z,lz);
  return __fadd_rn(__fadd_rn(__fmul_rn(dx,dx),__fmul_rn(dy,dy)),__fmul_rn(dz,dz));
}

__global__ __launch_bounds__(1024, 4) void fps_kernel(const float* __restrict__ pc){
  __shared__ float4 sX[LDS_G*1024], sY[LDS_G*1024], sZ[LDS_G*1024];  // 144 KB
  __shared__ float s_val[16];
  __shared__ int   s_idx[16];
  __shared__ float s_last[3];

  const int blk = blockIdx.x;
  const int b   = blk >> 3;          // batch
  const int s   = blk & 7;           // slice
  const int tid = threadIdx.x;
  const int lane = tid & 63, wave = tid >> 6;
  const size_t bN = (size_t)b*NPTS;
  const int soff = s*SLICE;

  // ---- one-time load: regs (j=0..3) and LDS (j=4..6), sanitized, from AoS pc ----
  float rx[REG_G*4], ry[REG_G*4], rz[REG_G*4];
#pragma unroll
  for (int j=0;j<REG_G+LDS_G;j++){
    int p0 = soff + j*4096 + tid*4;
    const float* src = pc + (bN + p0)*3;
    float4 A = *(const float4*)(src);
    float4 Bv= *(const float4*)(src+4);
    float4 C = *(const float4*)(src+8);
    float v[12] = {A.x,A.y,A.z,A.w,Bv.x,Bv.y,Bv.z,Bv.w,C.x,C.y,C.z,C.w};
#pragma unroll
    for (int q=0;q<12;q++) v[q] = san(v[q]);
    if (j < REG_G){
#pragma unroll
      for (int c=0;c<4;c++){ rx[j*4+c]=v[3*c]; ry[j*4+c]=v[3*c+1]; rz[j*4+c]=v[3*c+2]; }
    } else {
      sX[(j-REG_G)*1024+tid] = make_float4(v[0],v[3],v[6],v[9]);
      sY[(j-REG_G)*1024+tid] = make_float4(v[1],v[4],v[7],v[10]);
      sZ[(j-REG_G)*1024+tid] = make_float4(v[2],v[5],v[8],v[11]);
    }
  }

  float d[32];
#pragma unroll
  for (int i=0;i<32;i++) d[i] = __builtin_huge_valf();

  // first sample = sanitized point 0 (uniform scalar loads)
  float lx = san(pc[bN*3+0]), ly = san(pc[bN*3+1]), lz = san(pc[bN*3+2]);
  if (s==0 && tid<3) g_samp[(size_t)b*KSAMP*3 + tid] = san(pc[bN*3 + tid]);
  __syncthreads();   // LDS coords visible

  for (int k=1; k<KSAMP; k++){
    // issue global-group loads first (L2-resident region)
    size_t gb = bN + soff + (size_t)7*4096 + tid*4;
    float4 gx = *(const float4*)(g_px+gb);
    float4 gy = *(const float4*)(g_py+gb);
    float4 gz = *(const float4*)(g_pz+gb);

    float bestv = -1.0f; int besti = 0;
#define UPD(DX,DY,DZ,DI,IDX) { \
      float dd_ = dist3(DX,DY,DZ,lx,ly,lz); \
      float nd_ = fminf(d[DI], dd_); \
      d[DI] = nd_; \
      if (nd_ > bestv){ bestv = nd_; besti = (IDX); } }
    // register groups j=0..3
#pragma unroll
    for (int j=0;j<REG_G;j++){
#pragma unroll
      for (int c=0;c<4;c++)
        UPD(rx[j*4+c], ry[j*4+c], rz[j*4+c], j*4+c, soff + j*4096 + tid*4 + c)
    }
    // LDS groups j=4..6 (load just-in-time to limit register liveness)
#pragma unroll
    for (int j=0;j<LDS_G;j++){
      float4 X = sX[j*1024+tid], Y = sY[j*1024+tid], Z = sZ[j*1024+tid];
      float xs[4]={X.x,X.y,X.z,X.w}, ys[4]={Y.x,Y.y,Y.z,Y.w}, zs[4]={Z.x,Z.y,Z.z,Z.w};
#pragma unroll
      for (int c=0;c<4;c++)
        UPD(xs[c], ys[c], zs[c], (REG_G+j)*4+c, soff + (REG_G+j)*4096 + tid*4 + c)
    }
    // global group j=7
    {
      float xs[4]={gx.x,gx.y,gx.z,gx.w}, ys[4]={gy.x,gy.y,gy.z,gy.w}, zs[4]={gz.x,gz.y,gz.z,gz.w};
#pragma unroll
      for (int c=0;c<4;c++)
        UPD(xs[c], ys[c], zs[c], 28+c, soff + 7*4096 + tid*4 + c)
    }
#undef UPD

    // intra-wave argmax (first-index tie-break)
#pragma unroll
    for (int off=32; off; off>>=1){
      float ov = __shfl_down(bestv, off);
      int   oi = __shfl_down(besti, off);
      if (ov > bestv || (ov == bestv && oi < besti)){ bestv=ov; besti=oi; }
    }
    if (lane==0){ s_val[wave]=bestv; s_idx[wave]=besti; }
    __syncthreads();

    if (wave==0){
      // 16-lane cross-wave reduce (butterfly -> all lanes hold block candidate)
      float bv = s_val[lane & 15]; int bi = s_idx[lane & 15];
#pragma unroll
      for (int m=8; m; m>>=1){
        float ov = __shfl_xor(bv, m);
        int   oi = __shfl_xor(bi, m);
        if (ov > bv || (ov == bv && oi < bi)){ bv=ov; bi=oi; }
      }
      // publish packed candidate: [k:8][val:32][0xFFFFFF^idx:24]
      unsigned long long key = ((unsigned long long)(unsigned)k << 56)
                             | ((unsigned long long)__float_as_uint(bv) << 24)
                             | (unsigned long long)(0xFFFFFFu ^ (unsigned)bi);
      if (lane==0)
        __hip_atomic_store(&g_slot[b][k&1][s], key, __ATOMIC_RELEASE, __HIP_MEMORY_SCOPE_AGENT);
      // parallel poll: lane q watches slice q
      unsigned long long pay = 0;
      if (lane < NBLK_PER_B){
        unsigned long long v;
        do {
          v = __hip_atomic_load(&g_slot[b][k&1][lane], __ATOMIC_RELAXED, __HIP_MEMORY_SCOPE_AGENT);
        } while ((unsigned)(v >> 56) != (unsigned)k);
        pay = v & 0x00FFFFFFFFFFFFFFull;
      }
      // 8-lane max butterfly on payload (u64 via 2x32 shuffles)
#pragma unroll
      for (int m=4; m; m>>=1){
        unsigned lo = (unsigned)pay, hi = (unsigned)(pay >> 32);
        unsigned lo2 = __shfl_xor(lo, m), hi2 = __shfl_xor(hi, m);
        unsigned long long o = ((unsigned long long)hi2 << 32) | lo2;
        if (o > pay) pay = o;
      }
      int w = (int)(0xFFFFFFu ^ (unsigned)(pay & 0xFFFFFFu));
      if (lane < 3){
        float cv = san(pc[(bN + (size_t)w)*3 + lane]);
        s_last[lane] = cv;
        if (s==0) g_samp[((size_t)b*KSAMP + k)*3 + lane] = cv;
      }
    }
    __syncthreads();
    lx=s_last[0]; ly=s_last[1]; lz=s_last[2];
  }
}

// ---------------- normalize + Fourier encode ----------------
template<int OP>  // 0 sum, 1 max, 2 min
__device__ __forceinline__ float blk_red(float v, float* s4){
  int tid = threadIdx.x;
#pragma unroll
  for (int off=32; off; off>>=1){
    float o = __shfl_down(v, off);
    v = (OP==0) ? v+o : ((OP==1) ? fmaxf(v,o) : fminf(v,o));
  }
  if ((tid&63)==0) s4[tid>>6] = v;
  __syncthreads();
  float r0=s4[0], r1=s4[1], r2=s4[2], r3=s4[3];
  float r = (OP==0) ? ((r0+r1)+(r2+r3))
          : ((OP==1) ? fmaxf(fmaxf(r0,r1),fmaxf(r2,r3))
                     : fminf(fminf(r0,r1),fminf(r2,r3)));
  __syncthreads();
  return r;
}

__global__ __launch_bounds__(256) void norm_encode(){
  __shared__ float s4[4];
  int b = blockIdx.x, k = threadIdx.x;
  const float* sp = &g_samp[((size_t)b*KSAMP + k)*3];
  float x = sp[0], y = sp[1], z = sp[2];

  float cx = blk_red<0>(x, s4) * (1.0f/KSAMP);
  float cy = blk_red<0>(y, s4) * (1.0f/KSAMP);
  float cz = blk_red<0>(z, s4) * (1.0f/KSAMP);

  float ux = __fsub_rn(x,cx), uy = __fsub_rn(y,cy), uz = __fsub_rn(z,cz);

  float mxx = blk_red<1>(ux, s4), mnx = blk_red<2>(ux, s4);
  float mxy = blk_red<1>(uy, s4), mny = blk_red<2>(uy, s4);
  float mxz = blk_red<1>(uz, s4), mnz = blk_red<2>(uz, s4);
  float bx = __fsub_rn(mxx,mnx), by = __fsub_rn(mxy,mny), bz = __fsub_rn(mxz,mnz);
  float md = fmaxf(fmaxf(bx,by),bz);
  float scale = (md > 1e-8f) ? md : 1.0f;

  float n3[3] = { __fdiv_rn(ux,scale), __fdiv_rn(uy,scale), __fdiv_rn(uz,scale) };

  float* e = &g_enc[((size_t)b*KSAMP + k)*INDIM];
#pragma unroll
  for (int c=0;c<3;c++){
    float base = n3[c];
#pragma unroll
    for (int f=0; f<NF; f++){
      float t = __fmul_rn(base, (float)(1<<f));
      float a = __fmul_rn(t, PI_F);
      e[c*2*NF + f*2 + 0] = sinf(a);
      e[c*2*NF + f*2 + 1] = cosf(a);
    }
  }
}

// ---------------- GEMM ----------------
__global__ __launch_bounds__(256) void gemm_kernel(const float* __restrict__ bias,
                                                   float* __restrict__ out){
  __shared__ float s_enc[4*INDIM];
  int blk = blockIdx.x, tid = threadIdx.x;
  int row0 = blk*4;                         // 4 (b,k) rows per block
  if (tid < 4*INDIM) s_enc[tid] = g_enc[(size_t)row0*INDIM + tid];
  __syncthreads();

  float acc[4][3] = {};
  for (int d=0; d<INDIM; d++){
    float w0 = g_Wt[d*HID + tid];
    float w1 = g_Wt[d*HID + tid + 256];
    float w2 = g_Wt[d*HID + tid + 512];
#pragma unroll
    for (int r=0;r<4;r++){
      float ev = s_enc[r*INDIM + d];
      acc[r][0] = fmaf(ev, w0, acc[r][0]);
      acc[r][1] = fmaf(ev, w1, acc[r][1]);
      acc[r][2] = fmaf(ev, w2, acc[r][2]);
    }
  }
  float b0=bias[tid], b1=bias[tid+256], b2=bias[tid+512];
#pragma unroll
  for (int r=0;r<4;r++){
    size_t o = (size_t)(row0+r)*HID;
    out[o+tid]     = acc[r][0]+b0;
    out[o+tid+256] = acc[r][1]+b1;
    out[o+tid+512] = acc[r][2]+b2;
  }
}

// ---------------- launch ----------------
extern "C" void kernel_launch(void* const* d_in, const int* in_sizes, int n_in,
                              void* d_out, int out_size, void* d_ws, size_t ws_size,
                              hipStream_t stream){
  const float* pc   = (const float*)d_in[0];
  const float* W    = (const float*)d_in[1];
  const float* bias = (const float*)d_in[2];
  float* out = (float*)d_out;

  region_prepass<<<1024, 256, 0, stream>>>(pc);
  wtrans        <<<(INDIM*HID)/256, 256, 0, stream>>>(W);

  void* args[] = { (void*)&pc };
  hipLaunchCooperativeKernel((void*)fps_kernel, dim3(BATCH*NBLK_PER_B), dim3(1024),
                             args, 0, stream);

  norm_encode<<<BATCH, KSAMP, 0, stream>>>();
  gemm_kernel<<<(BATCH*KSAMP)/4, 256, 0, stream>>>(bias, out);
}

// Round 5
// 1664.755 us; speedup vs baseline: 11.1204x; 1.4931x over previous
//
#include <hip/hip_runtime.h>

#define BATCH 32
#define NPTS  262144
#define KSAMP 256
#define NF    10
#define INDIM 60
#define HID   768

#define NBLK_PER_B 8
#define SLICE (NPTS/NBLK_PER_B)   // 32768 points per block (one CU)
// per-thread point layout: 8 groups of 4 pts
//   j=0..3  -> registers (16 pts, 48 VGPRs)
//   j=4..6  -> LDS       (12 pts, 144 KB)
//   j=7     -> global SoA (4 pts, 48 KB/CU, L2-resident)
#define REG_G 4
#define LDS_G 3

#define PI_F 3.14159274101257324f  // float(math.pi)

// Static device scratch (rewritten every call before use)
__device__ float g_px[BATCH*NPTS];   // only group j=7 regions used
__device__ float g_py[BATCH*NPTS];
__device__ float g_pz[BATCH*NPTS];
__device__ float g_samp[BATCH*KSAMP*3];
__device__ float g_enc[(size_t)BATCH*KSAMP*INDIM];
__device__ float g_Wt[INDIM*HID];
__device__ unsigned long long g_slot[BATCH][2][NBLK_PER_B]; // [parity][slice], tag k in [63:56]

__device__ __forceinline__ float san(float v){
  float m = v*0.0f;                 // finite -> 0, inf/nan -> nan (no fast-math fold)
  return (m == 0.0f) ? v : 0.0f;
}

// ---------------- region prepass: sanitize + SoA for global-resident 1/8 ----------------
__global__ __launch_bounds__(256) void region_prepass(const float* __restrict__ pc){
  int bid = blockIdx.x;             // 1024 blocks
  int b   = bid >> 5;               // 32 blocks per batch
  int rem = bid & 31;
  int q   = rem*1024 + threadIdx.x*4;   // 0..32767 region-local (per batch)
  int s   = q >> 12;                    // slice (4096 pts of group 7 per slice)
  int o   = q & 4095;
  int p   = s*SLICE + 7*4096 + o;       // global point index in batch
  const float* src = pc + ((size_t)b*NPTS + p)*3;
  float4 A = *(const float4*)(src);
  float4 Bv= *(const float4*)(src+4);
  float4 C = *(const float4*)(src+8);
  float v[12] = {A.x,A.y,A.z,A.w,Bv.x,Bv.y,Bv.z,Bv.w,C.x,C.y,C.z,C.w};
#pragma unroll
  for (int j=0;j<12;j++) v[j] = san(v[j]);
  size_t base = (size_t)b*NPTS + p;
  *(float4*)(g_px+base) = make_float4(v[0],v[3],v[6],v[9]);
  *(float4*)(g_py+base) = make_float4(v[1],v[4],v[7],v[10]);
  *(float4*)(g_pz+base) = make_float4(v[2],v[5],v[8],v[11]);
}

// ---------------- W transpose + slot clear ----------------
__global__ __launch_bounds__(256) void wtrans(const float* __restrict__ W){
  int idx = blockIdx.x*256 + threadIdx.x;   // < 60*768 = 46080
  int d = idx / HID;
  int h = idx - d*HID;
  g_Wt[idx] = W[h*INDIM + d];
  if (blockIdx.x == 0 && threadIdx.x < 256){
    ((unsigned long long*)g_slot)[threadIdx.x*2+0] = 0ull;
    ((unsigned long long*)g_slot)[threadIdx.x*2+1] = 0ull;
  }
}

// ---------------- FPS ----------------
// Bit-exact vs reference: d = ((x-lx)^2 + (y-ly)^2) + (z-lz)^2, rn each step, no FMA.
__device__ __forceinline__ float dist3(float x,float y,float z,float lx,float ly,float lz){
  float dx=__fsub_rn(x,lx), dy=__fsub_rn(y,ly), dz=__fsub_rn(z,lz);
  return __fadd_rn(__fadd_rn(__fmul_rn(dx,dx),__fmul_rn(dy,dy)),__fmul_rn(dz,dz));
}

__global__ __launch_bounds__(1024, 4) void fps_kernel(const float* __restrict__ pc){
  __shared__ float4 sX[LDS_G*1024], sY[LDS_G*1024], sZ[LDS_G*1024];  // 144 KB
  __shared__ float s_val[16];
  __shared__ int   s_idx[16];
  __shared__ float s_last[3];

  // XCD-locality swizzle: assuming round-robin blockIdx%8 -> XCD, this puts
  // all 8 slices of a batch on ONE XCD (4 batches per XCD). Perf-only heuristic.
  const int blk = blockIdx.x;
  const int b   = (blk & 7) + 8*(blk >> 6);   // batch
  const int s   = (blk >> 3) & 7;             // slice
  const int tid = threadIdx.x;
  const int lane = tid & 63, wave = tid >> 6;
  const size_t bN = (size_t)b*NPTS;
  const int soff = s*SLICE;

  // ---- one-time load: regs (j=0..3) and LDS (j=4..6), sanitized, from AoS pc ----
  float rx[REG_G*4], ry[REG_G*4], rz[REG_G*4];
#pragma unroll
  for (int j=0;j<REG_G+LDS_G;j++){
    int p0 = soff + j*4096 + tid*4;
    const float* src = pc + (bN + p0)*3;
    float4 A = *(const float4*)(src);
    float4 Bv= *(const float4*)(src+4);
    float4 C = *(const float4*)(src+8);
    float v[12] = {A.x,A.y,A.z,A.w,Bv.x,Bv.y,Bv.z,Bv.w,C.x,C.y,C.z,C.w};
#pragma unroll
    for (int q=0;q<12;q++) v[q] = san(v[q]);
    if (j < REG_G){
#pragma unroll
      for (int c=0;c<4;c++){ rx[j*4+c]=v[3*c]; ry[j*4+c]=v[3*c+1]; rz[j*4+c]=v[3*c+2]; }
    } else {
      sX[(j-REG_G)*1024+tid] = make_float4(v[0],v[3],v[6],v[9]);
      sY[(j-REG_G)*1024+tid] = make_float4(v[1],v[4],v[7],v[10]);
      sZ[(j-REG_G)*1024+tid] = make_float4(v[2],v[5],v[8],v[11]);
    }
  }

  float d[32];
#pragma unroll
  for (int i=0;i<32;i++) d[i] = __builtin_huge_valf();

  // first sample = sanitized point 0 (uniform scalar loads)
  float lx = san(pc[bN*3+0]), ly = san(pc[bN*3+1]), lz = san(pc[bN*3+2]);
  if (s==0 && tid<3) g_samp[(size_t)b*KSAMP*3 + tid] = san(pc[bN*3 + tid]);
  __syncthreads();   // LDS coords visible

  for (int k=1; k<KSAMP; k++){
    // issue global-group loads first (L2-resident region)
    size_t gb = bN + soff + (size_t)7*4096 + tid*4;
    float4 gx = *(const float4*)(g_px+gb);
    float4 gy = *(const float4*)(g_py+gb);
    float4 gz = *(const float4*)(g_pz+gb);

    float bestv = -1.0f; int besti = 0;
#define UPD(DX,DY,DZ,DI,IDX) { \
      float dd_ = dist3(DX,DY,DZ,lx,ly,lz); \
      float nd_ = fminf(d[DI], dd_); \
      d[DI] = nd_; \
      if (nd_ > bestv){ bestv = nd_; besti = (IDX); } }
    // register groups j=0..3
#pragma unroll
    for (int j=0;j<REG_G;j++){
#pragma unroll
      for (int c=0;c<4;c++)
        UPD(rx[j*4+c], ry[j*4+c], rz[j*4+c], j*4+c, soff + j*4096 + tid*4 + c)
    }
    // LDS groups j=4..6 (load just-in-time to limit register liveness)
#pragma unroll
    for (int j=0;j<LDS_G;j++){
      float4 X = sX[j*1024+tid], Y = sY[j*1024+tid], Z = sZ[j*1024+tid];
      float xs[4]={X.x,X.y,X.z,X.w}, ys[4]={Y.x,Y.y,Y.z,Y.w}, zs[4]={Z.x,Z.y,Z.z,Z.w};
#pragma unroll
      for (int c=0;c<4;c++)
        UPD(xs[c], ys[c], zs[c], (REG_G+j)*4+c, soff + (REG_G+j)*4096 + tid*4 + c)
    }
    // global group j=7
    {
      float xs[4]={gx.x,gx.y,gx.z,gx.w}, ys[4]={gy.x,gy.y,gy.z,gy.w}, zs[4]={gz.x,gz.y,gz.z,gz.w};
#pragma unroll
      for (int c=0;c<4;c++)
        UPD(xs[c], ys[c], zs[c], 28+c, soff + 7*4096 + tid*4 + c)
    }
#undef UPD

    // intra-wave argmax (first-index tie-break)
#pragma unroll
    for (int off=32; off; off>>=1){
      float ov = __shfl_down(bestv, off);
      int   oi = __shfl_down(besti, off);
      if (ov > bestv || (ov == bestv && oi < besti)){ bestv=ov; besti=oi; }
    }
    if (lane==0){ s_val[wave]=bestv; s_idx[wave]=besti; }
    __syncthreads();

    if (wave==0){
      // 16-lane cross-wave reduce (butterfly -> all lanes hold block candidate)
      float bv = s_val[lane & 15]; int bi = s_idx[lane & 15];
#pragma unroll
      for (int m=8; m; m>>=1){
        float ov = __shfl_xor(bv, m);
        int   oi = __shfl_xor(bi, m);
        if (ov > bv || (ov == bv && oi < bi)){ bv=ov; bi=oi; }
      }
      // publish packed candidate: [k:8][val:32][0xFFFFFF^idx:24]
      // RELAXED is sufficient: the tagged u64 is self-contained (atomicity,
      // not ordering, carries the protocol); winner coords come from
      // read-only pc; max inter-block skew is 1 iteration (parity buffer).
      unsigned long long key = ((unsigned long long)(unsigned)k << 56)
                             | ((unsigned long long)__float_as_uint(bv) << 24)
                             | (unsigned long long)(0xFFFFFFu ^ (unsigned)bi);
      if (lane==0)
        __hip_atomic_store(&g_slot[b][k&1][s], key, __ATOMIC_RELAXED, __HIP_MEMORY_SCOPE_AGENT);
      // parallel poll: lane q watches slice q; s_sleep backoff to keep LLC
      // bank pressure off the publisher's store.
      unsigned long long pay = 0;
      if (lane < NBLK_PER_B){
        unsigned long long v;
        for (;;){
          v = __hip_atomic_load(&g_slot[b][k&1][lane], __ATOMIC_RELAXED, __HIP_MEMORY_SCOPE_AGENT);
          if ((unsigned)(v >> 56) == (unsigned)k) break;
          __builtin_amdgcn_s_sleep(1);
        }
        pay = v & 0x00FFFFFFFFFFFFFFull;
      }
      // 8-lane max butterfly on payload (u64 via 2x32 shuffles)
#pragma unroll
      for (int m=4; m; m>>=1){
        unsigned lo = (unsigned)pay, hi = (unsigned)(pay >> 32);
        unsigned lo2 = __shfl_xor(lo, m), hi2 = __shfl_xor(hi, m);
        unsigned long long o = ((unsigned long long)hi2 << 32) | lo2;
        if (o > pay) pay = o;
      }
      int w = (int)(0xFFFFFFu ^ (unsigned)(pay & 0xFFFFFFu));
      if (lane < 3){
        float cv = san(pc[(bN + (size_t)w)*3 + lane]);
        s_last[lane] = cv;
        if (s==0) g_samp[((size_t)b*KSAMP + k)*3 + lane] = cv;
      }
    }
    __syncthreads();
    lx=s_last[0]; ly=s_last[1]; lz=s_last[2];
  }
}

// ---------------- normalize + Fourier encode ----------------
template<int OP>  // 0 sum, 1 max, 2 min
__device__ __forceinline__ float blk_red(float v, float* s4){
  int tid = threadIdx.x;
#pragma unroll
  for (int off=32; off; off>>=1){
    float o = __shfl_down(v, off);
    v = (OP==0) ? v+o : ((OP==1) ? fmaxf(v,o) : fminf(v,o));
  }
  if ((tid&63)==0) s4[tid>>6] = v;
  __syncthreads();
  float r0=s4[0], r1=s4[1], r2=s4[2], r3=s4[3];
  float r = (OP==0) ? ((r0+r1)+(r2+r3))
          : ((OP==1) ? fmaxf(fmaxf(r0,r1),fmaxf(r2,r3))
                     : fminf(fminf(r0,r1),fminf(r2,r3)));
  __syncthreads();
  return r;
}

__global__ __launch_bounds__(256) void norm_encode(){
  __shared__ float s4[4];
  int b = blockIdx.x, k = threadIdx.x;
  const float* sp = &g_samp[((size_t)b*KSAMP + k)*3];
  float x = sp[0], y = sp[1], z = sp[2];

  float cx = blk_red<0>(x, s4) * (1.0f/KSAMP);
  float cy = blk_red<0>(y, s4) * (1.0f/KSAMP);
  float cz = blk_red<0>(z, s4) * (1.0f/KSAMP);

  float ux = __fsub_rn(x,cx), uy = __fsub_rn(y,cy), uz = __fsub_rn(z,cz);

  float mxx = blk_red<1>(ux, s4), mnx = blk_red<2>(ux, s4);
  float mxy = blk_red<1>(uy, s4), mny = blk_red<2>(uy, s4);
  float mxz = blk_red<1>(uz, s4), mnz = blk_red<2>(uz, s4);
  float bx = __fsub_rn(mxx,mnx), by = __fsub_rn(mxy,mny), bz = __fsub_rn(mxz,mnz);
  float md = fmaxf(fmaxf(bx,by),bz);
  float scale = (md > 1e-8f) ? md : 1.0f;

  float n3[3] = { __fdiv_rn(ux,scale), __fdiv_rn(uy,scale), __fdiv_rn(uz,scale) };

  float* e = &g_enc[((size_t)b*KSAMP + k)*INDIM];
#pragma unroll
  for (int c=0;c<3;c++){
    float base = n3[c];
#pragma unroll
    for (int f=0; f<NF; f++){
      float t = __fmul_rn(base, (float)(1<<f));
      float a = __fmul_rn(t, PI_F);
      e[c*2*NF + f*2 + 0] = sinf(a);
      e[c*2*NF + f*2 + 1] = cosf(a);
    }
  }
}

// ---------------- GEMM ----------------
__global__ __launch_bounds__(256) void gemm_kernel(const float* __restrict__ bias,
                                                   float* __restrict__ out){
  __shared__ float s_enc[4*INDIM];
  int blk = blockIdx.x, tid = threadIdx.x;
  int row0 = blk*4;                         // 4 (b,k) rows per block
  if (tid < 4*INDIM) s_enc[tid] = g_enc[(size_t)row0*INDIM + tid];
  __syncthreads();

  float acc[4][3] = {};
  for (int d=0; d<INDIM; d++){
    float w0 = g_Wt[d*HID + tid];
    float w1 = g_Wt[d*HID + tid + 256];
    float w2 = g_Wt[d*HID + tid + 512];
#pragma unroll
    for (int r=0;r<4;r++){
      float ev = s_enc[r*INDIM + d];
      acc[r][0] = fmaf(ev, w0, acc[r][0]);
      acc[r][1] = fmaf(ev, w1, acc[r][1]);
      acc[r][2] = fmaf(ev, w2, acc[r][2]);
    }
  }
  float b0=bias[tid], b1=bias[tid+256], b2=bias[tid+512];
#pragma unroll
  for (int r=0;r<4;r++){
    size_t o = (size_t)(row0+r)*HID;
    out[o+tid]     = acc[r][0]+b0;
    out[o+tid+256] = acc[r][1]+b1;
    out[o+tid+512] = acc[r][2]+b2;
  }
}

// ---------------- launch ----------------
extern "C" void kernel_launch(void* const* d_in, const int* in_sizes, int n_in,
                              void* d_out, int out_size, void* d_ws, size_t ws_size,
                              hipStream_t stream){
  const float* pc   = (const float*)d_in[0];
  const float* W    = (const float*)d_in[1];
  const float* bias = (const float*)d_in[2];
  float* out = (float*)d_out;

  region_prepass<<<1024, 256, 0, stream>>>(pc);
  wtrans        <<<(INDIM*HID)/256, 256, 0, stream>>>(W);

  void* args[] = { (void*)&pc };
  hipLaunchCooperativeKernel((void*)fps_kernel, dim3(BATCH*NBLK_PER_B), dim3(1024),
                             args, 0, stream);

  norm_encode<<<BATCH, KSAMP, 0, stream>>>();
  gemm_kernel<<<(BATCH*KSAMP)/4, 256, 0, stream>>>(bias, out);
}